// Round 14
// baseline (96.825 us; speedup 1.0000x reference)
//
#include <hip/hip_runtime.h>
#include <hip/hip_bf16.h>

#define NPTS   300
#define HW_SZ  1920
#define NH     8
#define TOTAL  (NPTS * HW_SZ)    // 576000
#define L2T128 0.10381025293350249f   // log2(10000)/128
#define KREVL2 3.9923601817f     // log2(100/(2*pi)) -> angles in revolutions

// f(delta) table: 32768 rows x 8 bf16 heads over [-16,16), h = 2^-10.
// |delta| <= ln(60/1e-5) = 15.61 < 16. Verified numerics (R3: absmax 0.0078125).
#define TBL_N 32768

typedef __attribute__((ext_vector_type(4))) float floatx4;

// f32 -> bf16 (round-half-up, matches prior rounds' pack numerics)
__device__ __forceinline__ unsigned short bf16_hu(float x) {
    return (unsigned short)((__float_as_uint(x) + 0x8000u) >> 16);
}
__device__ __forceinline__ float blo(unsigned u) { return __uint_as_float(u << 16); }
__device__ __forceinline__ float bhi(unsigned u) { return __uint_as_float(u & 0xffff0000u); }

// Builder: tbl16[e*8+h] = bf16( b[h] + sum_i Ws[i,h] sin(k_i d_e) + Wc[i,h] cos(k_i d_e) )
// 1024 blocks x 256 thr; thread = (entry-lane el 0..31, freq-chunk ch 0..7: 16 freqs).
// Native v_sin/v_cos in revolutions (|angle| <= 249 rev < 256 domain).
__global__ __launch_bounds__(256) void dre_tbuild(const float* __restrict__ W,
                                                  const float* __restrict__ b,
                                                  unsigned short* __restrict__ tbl16)
{
    __shared__ float red[8 * 264];            // [c][el*8+h], 8.25 KB, 16B-aligned rows

    const int tid = threadIdx.x;
    const int el  = tid >> 3, ch = tid & 7;
    const int e   = blockIdx.x * 32 + el;
    const float delta = -16.0f + (float)e * (1.0f / 1024.0f);

    float acc[NH];
#pragma unroll
    for (int h = 0; h < NH; ++h) acc[h] = 0.0f;

    const int i0 = ch * 16;
#pragma unroll
    for (int j = 0; j < 16; ++j) {
        const int i = i0 + j;
        const float krev = exp2f(KREVL2 - (float)i * L2T128);
        const float a = krev * delta;
        const float s = __builtin_amdgcn_sinf(a);
        const float c = __builtin_amdgcn_cosf(a);
        const float4 ws0 = *(const float4*)(W + i * 16);      // Ws h0..3
        const float4 ws1 = *(const float4*)(W + i * 16 + 4);  // Ws h4..7
        const float4 wc0 = *(const float4*)(W + i * 16 + 8);  // Wc h0..3
        const float4 wc1 = *(const float4*)(W + i * 16 + 12); // Wc h4..7
        acc[0] = fmaf(s, ws0.x, fmaf(c, wc0.x, acc[0]));
        acc[1] = fmaf(s, ws0.y, fmaf(c, wc0.y, acc[1]));
        acc[2] = fmaf(s, ws0.z, fmaf(c, wc0.z, acc[2]));
        acc[3] = fmaf(s, ws0.w, fmaf(c, wc0.w, acc[3]));
        acc[4] = fmaf(s, ws1.x, fmaf(c, wc1.x, acc[4]));
        acc[5] = fmaf(s, ws1.y, fmaf(c, wc1.y, acc[5]));
        acc[6] = fmaf(s, ws1.z, fmaf(c, wc1.z, acc[6]));
        acc[7] = fmaf(s, ws1.w, fmaf(c, wc1.w, acc[7]));
    }
    // red[ch][el*8+h]: base (ch*264 + el*8)*4 B is 16B-aligned -> 2x b128 writes
    *(float4*)&red[ch * 264 + el * 8]     = make_float4(acc[0], acc[1], acc[2], acc[3]);
    *(float4*)&red[ch * 264 + el * 8 + 4] = make_float4(acc[4], acc[5], acc[6], acc[7]);
    __syncthreads();

    // reduce: thread (el2, h) sums 8 chunks; banks 2-way max
    const int el2 = tid >> 3, h2 = tid & 7;
    float sum = b[h2];
#pragma unroll
    for (int c2 = 0; c2 < 8; ++c2)
        sum += red[c2 * 264 + el2 * 8 + h2];
    // coalesced ushort store: consecutive tid -> consecutive 2B
    tbl16[(size_t)(blockIdx.x * 32 + el2) * NH + h2] = bf16_hu(sum);
}

// Main: one thread per (n, hw) point. 2400 blocks (9.4/CU) -> deep pipeline.
// grid (8, 300): blockIdx.y = n, hw = blockIdx.x*256 + tid.
__global__ __launch_bounds__(256) void dre_tmain(const float* __restrict__ pd,
                                                 const float* __restrict__ dm,
                                                 const uint4* __restrict__ tbl,
                                                 float* __restrict__ out)
{
    const int n  = blockIdx.y;
    const int hw = blockIdx.x * 256 + threadIdx.x;
    if (hw >= HW_SZ) return;

    const float lp = __logf(fmaxf(pd[n], 0.0f) + 1e-5f);   // n uniform per block
    const float ld = __logf(dm[hw] + 1e-5f);                // coalesced
    const float t  = fmaf(lp - ld, 1024.0f, 16384.0f);      // (delta+16)*1024
    const float jf = floorf(t);
    int j = (int)jf;
    j = max(0, min(j, TBL_N - 2));
    const float f = t - jf;

    const uint4 r0 = tbl[j];                                // row j   (8 bf16)
    const uint4 r1 = tbl[j + 1];                            // row j+1

    const float a0 = blo(r0.x), a1 = bhi(r0.x), a2 = blo(r0.y), a3 = bhi(r0.y);
    const float a4 = blo(r0.z), a5 = bhi(r0.z), a6 = blo(r0.w), a7 = bhi(r0.w);
    const float b0 = blo(r1.x), b1 = bhi(r1.x), b2 = blo(r1.y), b3 = bhi(r1.y);
    const float b4 = blo(r1.z), b5 = bhi(r1.z), b6 = blo(r1.w), b7 = bhi(r1.w);

    float v[NH];
    v[0] = fmaxf(fmaf(f, b0 - a0, a0), 0.0f);
    v[1] = fmaxf(fmaf(f, b1 - a1, a1), 0.0f);
    v[2] = fmaxf(fmaf(f, b2 - a2, a2), 0.0f);
    v[3] = fmaxf(fmaf(f, b3 - a3, a3), 0.0f);
    v[4] = fmaxf(fmaf(f, b4 - a4, a4), 0.0f);
    v[5] = fmaxf(fmaf(f, b5 - a5, a5), 0.0f);
    v[6] = fmaxf(fmaf(f, b6 - a6, a6), 0.0f);
    v[7] = fmaxf(fmaf(f, b7 - a7, a7), 0.0f);

    const size_t base = (size_t)n * HW_SZ + hw;
#pragma unroll
    for (int h = 0; h < NH; ++h)
        out[(size_t)h * TOTAL + base] = v[h];               // coalesced per h
}

extern "C" void kernel_launch(void* const* d_in, const int* in_sizes, int n_in,
                              void* d_out, int out_size, void* d_ws, size_t ws_size,
                              hipStream_t stream) {
    const float* pd = (const float*)d_in[0];
    const float* dm = (const float*)d_in[1];
    const float* W  = (const float*)d_in[2];
    const float* b  = (const float*)d_in[3];
    float* out = (float*)d_out;
    unsigned short* tbl16 = (unsigned short*)d_ws;          // 32768*8*2 = 512 KB

    dre_tbuild<<<TBL_N / 32, 256, 0, stream>>>(W, b, tbl16);
    dre_tmain<<<dim3(8, NPTS), 256, 0, stream>>>(pd, dm, (const uint4*)tbl16, out);
}

// Round 15
// 72.870 us; speedup vs baseline: 1.3288x; 1.3288x over previous
//
#include <hip/hip_runtime.h>
#include <hip/hip_bf16.h>

#define NPTS   300
#define HW_SZ  1920
#define TOTAL  (NPTS * HW_SZ)    // 576000
#define NCOL   2400              // columns c = n*8 + h
#define L2T128 0.10381025293350249f   // log2(10000)/128
#define KREVL2 3.9923601817f     // log2(100/(2*pi)) -> angles in revolutions

#define BM   128
#define BN   64
#define LDK2 136                 // BsP/BsQ row stride (shorts)
#define SNP  132                 // snq/cnq row stride (floats)
#define WPP  132                 // wpk row stride (dwords)
#define MT   15                  // 1920 / 128
#define CT   38                  // 2432 / 64

typedef __attribute__((ext_vector_type(8))) short short8;
typedef __attribute__((ext_vector_type(4))) float floatx4;

union frag_u { unsigned u[4]; short8 s; };

// pack two f32 -> bf16 pair (round-half-up): 2 v_add + 1 v_perm
__device__ __forceinline__ unsigned pk_bf16(float lo, float hi) {
    return __builtin_amdgcn_perm(__float_as_uint(hi) + 0x8000u,
                                 __float_as_uint(lo) + 0x8000u,
                                 0x07060302u);
}
__device__ __forceinline__ float blo(unsigned u) { return __uint_as_float(u << 16); }
__device__ __forceinline__ float bhi(unsigned u) { return __uint_as_float(u & 0xffff0000u); }

// out[hw, c] = relu( sum_i cos(k_i ld)*P[i,c] + sin(k_i ld)*Q[i,c] + b[h] )
//   P = Ws*sin(k lp) + Wc*cos(k lp),  Q = Wc*sin(k lp) - Ws*cos(k lp)
// All A-fragments computed PRE-barrier from direct global dm loads (overlaps
// setup-load latency); post-barrier path: B-build -> barrier -> ds_read+MFMA only.
// Angles in revolutions, native v_sin/v_cos (|angle| <= 249 rev < 256 domain).
__global__ __launch_bounds__(256, 3) void dre_v15(const float* __restrict__ pd,
                                                  const float* __restrict__ dm,
                                                  const float* __restrict__ W,
                                                  const float* __restrict__ b,
                                                  float* __restrict__ out)
{
    __shared__ float    snq[8 * SNP];        //  4.2 KB  sin(krev_i lp(n))
    __shared__ float    cnq[8 * SNP];        //  4.2 KB
    __shared__ unsigned wpk[8 * WPP];        //  4.2 KB  (bf16 ws | bf16 wc<<16)[h][i]
    __shared__ unsigned short BsP[BN * LDK2];// 17.4 KB
    __shared__ unsigned short BsQ[BN * LDK2];// 17.4 KB  => 47.5 KB, 3 blk/CU

    const int tid  = threadIdx.x;
    const int m0   = blockIdx.x * BM;
    const int c0   = blockIdx.y * BN;
    const int n0   = c0 >> 3;
    const int w    = tid >> 6, lane = tid & 63, quad = lane >> 4, l16 = lane & 15;

    // ---- phase 0a: issue own-row dm loads early (latency overlapped below) ----
    const float dv0 = dm[m0 + w * 32 + l16];
    const float dv1 = dm[m0 + w * 32 + 16 + l16];

    // ---- phase 0b: cooperative setup (W pack + sn/cn), racing no one ----
    {   // W -> packed bf16 pairs, transposed [h][i]; covers 8 x 128
        const int h = tid & 7, i0 = (tid >> 3) * 4;
        unsigned pk[4];
#pragma unroll
        for (int j = 0; j < 4; ++j)
            pk[j] = pk_bf16(W[(i0 + j) * 16 + h], W[(i0 + j) * 16 + 8 + h]);
        *(uint4*)&wpk[h * WPP + i0] = make_uint4(pk[0], pk[1], pk[2], pk[3]);
    }
    {   // sn/cn for the block's 8 n's (angles in revolutions)
        const int nl = tid >> 5, i0 = (tid & 31) * 4;
        const int nn = n0 + nl;
        const float pv = (nn < NPTS) ? pd[nn] : 0.0f;     // pad n masked at store
        const float lp = __logf(fmaxf(pv, 0.0f) + 1e-5f);
        float s[4], c[4];
#pragma unroll
        for (int j = 0; j < 4; ++j) {
            const float a = exp2f(KREVL2 - (float)(i0 + j) * L2T128) * lp;
            s[j] = __builtin_amdgcn_sinf(a);
            c[j] = __builtin_amdgcn_cosf(a);
        }
        *(float4*)&snq[nl * SNP + i0] = make_float4(s[0], s[1], s[2], s[3]);
        *(float4*)&cnq[nl * SNP + i0] = make_float4(c[0], c[1], c[2], c[3]);
    }

    // ---- phase 0c: ALL A-fragments pre-barrier (pure registers) ----
    const float ldr0 = __logf(dv0 + 1e-5f);
    const float ldr1 = __logf(dv1 + 1e-5f);
    frag_u cf[2][2][2], sf[2][2][2];                      // [ib][ks][mi]
#pragma unroll
    for (int ib = 0; ib < 2; ++ib) {
#pragma unroll
        for (int ks = 0; ks < 2; ++ks) {
            const int kb = ib * 64 + ks * 32 + quad * 8;
            float s0[8], c0v[8], s1[8], c1v[8];
#pragma unroll
            for (int j = 0; j < 8; ++j) {
                const float krev = exp2f(KREVL2 - (float)(kb + j) * L2T128);
                const float a0 = krev * ldr0, a1 = krev * ldr1;
                s0[j]  = __builtin_amdgcn_sinf(a0);
                c0v[j] = __builtin_amdgcn_cosf(a0);
                s1[j]  = __builtin_amdgcn_sinf(a1);
                c1v[j] = __builtin_amdgcn_cosf(a1);
            }
#pragma unroll
            for (int r = 0; r < 4; ++r) {
                cf[ib][ks][0].u[r] = pk_bf16(c0v[2*r], c0v[2*r+1]);
                sf[ib][ks][0].u[r] = pk_bf16(s0[2*r],  s0[2*r+1]);
                cf[ib][ks][1].u[r] = pk_bf16(c1v[2*r], c1v[2*r+1]);
                sf[ib][ks][1].u[r] = pk_bf16(s1[2*r],  s1[2*r+1]);
            }
        }
    }

    __syncthreads();                                      // snq/cnq/wpk ready

    // ---- B-build (R12-verified): BsP/BsQ full i in [0,128), one pass ----
    {
        const int bcr = tid >> 2, q = tid & 3;            // c row, 32-i span
        const int bnl = bcr >> 3, bh = bcr & 7;
#pragma unroll
        for (int half = 0; half < 2; ++half) {
            const int ib0 = q * 32 + half * 16;
            unsigned pp[8], qq[8];
#pragma unroll
            for (int g = 0; g < 4; ++g) {
                const int i4 = ib0 + g * 4;
                const float4 s4 = *(const float4*)&snq[bnl * SNP + i4];
                const float4 c4 = *(const float4*)&cnq[bnl * SNP + i4];
                const uint4  w4 = *(const uint4*)&wpk[bh * WPP + i4];
                const float ws0 = blo(w4.x), wc0 = bhi(w4.x);
                const float ws1 = blo(w4.y), wc1 = bhi(w4.y);
                const float ws2 = blo(w4.z), wc2 = bhi(w4.z);
                const float ws3 = blo(w4.w), wc3 = bhi(w4.w);
                const float P0 = ws0*s4.x + wc0*c4.x, Q0 = wc0*s4.x - ws0*c4.x;
                const float P1 = ws1*s4.y + wc1*c4.y, Q1 = wc1*s4.y - ws1*c4.y;
                const float P2 = ws2*s4.z + wc2*c4.z, Q2 = wc2*s4.z - ws2*c4.z;
                const float P3 = ws3*s4.w + wc3*c4.w, Q3 = wc3*s4.w - ws3*c4.w;
                pp[2*g] = pk_bf16(P0, P1);  pp[2*g+1] = pk_bf16(P2, P3);
                qq[2*g] = pk_bf16(Q0, Q1);  qq[2*g+1] = pk_bf16(Q2, Q3);
            }
            *(uint4*)&BsP[bcr * LDK2 + ib0]     = make_uint4(pp[0], pp[1], pp[2], pp[3]);
            *(uint4*)&BsP[bcr * LDK2 + ib0 + 8] = make_uint4(pp[4], pp[5], pp[6], pp[7]);
            *(uint4*)&BsQ[bcr * LDK2 + ib0]     = make_uint4(qq[0], qq[1], qq[2], qq[3]);
            *(uint4*)&BsQ[bcr * LDK2 + ib0 + 8] = make_uint4(qq[4], qq[5], qq[6], qq[7]);
        }
    }
    __syncthreads();

    // ---- MFMA phase: pure ds_read + MFMA (A-frags already in registers) ----
    floatx4 acc[2][4];
#pragma unroll
    for (int mi = 0; mi < 2; ++mi)
#pragma unroll
        for (int nf = 0; nf < 4; ++nf) acc[mi][nf] = (floatx4){0.f, 0.f, 0.f, 0.f};

#pragma unroll
    for (int ib = 0; ib < 2; ++ib) {
#pragma unroll
        for (int ks = 0; ks < 2; ++ks) {
            const int koff = ib * 64 + ks * 32 + quad * 8;
#pragma unroll
            for (int nf = 0; nf < 4; ++nf) {
                short8 bp = *(const short8*)&BsP[(nf * 16 + l16) * LDK2 + koff];
                acc[0][nf] = __builtin_amdgcn_mfma_f32_16x16x32_bf16(cf[ib][ks][0].s, bp, acc[0][nf], 0, 0, 0);
                acc[1][nf] = __builtin_amdgcn_mfma_f32_16x16x32_bf16(cf[ib][ks][1].s, bp, acc[1][nf], 0, 0, 0);
                short8 bq = *(const short8*)&BsQ[(nf * 16 + l16) * LDK2 + koff];
                acc[0][nf] = __builtin_amdgcn_mfma_f32_16x16x32_bf16(sf[ib][ks][0].s, bq, acc[0][nf], 0, 0, 0);
                acc[1][nf] = __builtin_amdgcn_mfma_f32_16x16x32_bf16(sf[ib][ks][1].s, bq, acc[1][nf], 0, 0, 0);
            }
        }
    }

    // ---- epilogue (verified): C/D col=lane&15, row=quad*4+reg ----
    const float bias = b[lane & 7];
#pragma unroll
    for (int mi = 0; mi < 2; ++mi) {
#pragma unroll
        for (int nf = 0; nf < 4; ++nf) {
            const int c = c0 + nf * 16 + l16;
            if (c < NCOL) {
                const int n = c >> 3, h = c & 7;
                const int hw = m0 + w * 32 + mi * 16 + quad * 4;
                floatx4 v = acc[mi][nf];
                v.x = fmaxf(v.x + bias, 0.0f);
                v.y = fmaxf(v.y + bias, 0.0f);
                v.z = fmaxf(v.z + bias, 0.0f);
                v.w = fmaxf(v.w + bias, 0.0f);
                *(floatx4*)(out + (size_t)h * TOTAL + (size_t)n * HW_SZ + hw) = v;
            }
        }
    }
}

extern "C" void kernel_launch(void* const* d_in, const int* in_sizes, int n_in,
                              void* d_out, int out_size, void* d_ws, size_t ws_size,
                              hipStream_t stream) {
    const float* pd = (const float*)d_in[0];
    const float* dm = (const float*)d_in[1];
    const float* W  = (const float*)d_in[2];
    const float* b  = (const float*)d_in[3];
    float* out = (float*)d_out;

    dre_v15<<<dim3(MT, CT), 256, 0, stream>>>(pd, dm, W, b, out);
}

// Round 16
// 71.820 us; speedup vs baseline: 1.3482x; 1.0146x over previous
//
#include <hip/hip_runtime.h>
#include <hip/hip_bf16.h>

#define NPTS   300
#define HW_SZ  1920
#define TOTAL  (NPTS * HW_SZ)    // 576000
#define NCOL   2400              // columns c = n*8 + h
#define L2T128 0.10381025293350249f   // log2(10000)/128
#define KREVL2 3.9923601817f     // log2(100 / (2*pi)) -> angles in revolutions

#define BM   128
#define BN   64
#define LDK2 136                 // BsP/BsQ row stride (shorts)
#define SNP  132                 // snq/cnq row stride (floats)
#define WPP  132                 // wpk row stride (dwords)
#define MT   15                  // 1920 / 128
#define CT   38                  // 2432 / 64

typedef __attribute__((ext_vector_type(8))) short short8;
typedef __attribute__((ext_vector_type(4))) float floatx4;

union frag_u { unsigned u[4]; short8 s; };

// pack two f32 -> bf16 pair (round-half-up): 2 v_add + 1 v_perm
__device__ __forceinline__ unsigned pk_bf16(float lo, float hi) {
    return __builtin_amdgcn_perm(__float_as_uint(hi) + 0x8000u,
                                 __float_as_uint(lo) + 0x8000u,
                                 0x07060302u);
}
__device__ __forceinline__ float blo(unsigned u) { return __uint_as_float(u << 16); }
__device__ __forceinline__ float bhi(unsigned u) { return __uint_as_float(u & 0xffff0000u); }

// All angles in REVOLUTIONS (krev = k/2pi, max |angle| = 248.4 rev < 256 domain):
// raw v_sin_f32 / v_cos_f32, one instruction each.
// out[hw, c] = relu( sum_i cos*P + sin*Q + b[h] );  P,Q from angle-addition.
// R12 champion structure (71.9 us) with the ldm OOB race fixed.
__global__ __launch_bounds__(256, 3) void dre_v16(const float* __restrict__ pd,
                                                  const float* __restrict__ dm,
                                                  const float* __restrict__ W,
                                                  const float* __restrict__ b,
                                                  float* __restrict__ out)
{
    __shared__ float    kfr[128];            //  0.5 KB  krev[i]
    __shared__ float    ldm[BM];             //  0.5 KB
    __shared__ float    snq[8 * SNP];        //  4.2 KB  sin(krev_i lp(n)) [rev]
    __shared__ float    cnq[8 * SNP];        //  4.2 KB
    __shared__ unsigned wpk[8 * WPP];        //  4.2 KB  (bf16 ws | bf16 wc<<16)[h][i]
    __shared__ unsigned short BsP[BN * LDK2];// 17.4 KB
    __shared__ unsigned short BsQ[BN * LDK2];// 17.4 KB  => 48.4 KB, 3 blk/CU

    const int tid = threadIdx.x;
    const int m0  = blockIdx.x * BM;
    const int c0  = blockIdx.y * BN;
    const int n0  = c0 >> 3;

    // ---- setup (race-free: ldm[0..127] from tid 128..255 exactly) ----
    if (tid < 128) kfr[tid] = exp2f(KREVL2 - (float)tid * L2T128);
    else           ldm[tid - 128] = __logf(dm[m0 + tid - 128] + 1e-5f);
    {   // W -> packed bf16 pairs, transposed [h][i]
        const int h = tid & 7, i0 = (tid >> 3) * 4;
        unsigned pk[4];
#pragma unroll
        for (int j = 0; j < 4; ++j)
            pk[j] = pk_bf16(W[(i0 + j) * 16 + h], W[(i0 + j) * 16 + 8 + h]);
        *(uint4*)&wpk[h * WPP + i0] = make_uint4(pk[0], pk[1], pk[2], pk[3]);
    }
    {   // sn/cn for the block's 8 n's (angles in revolutions)
        const int nl = tid >> 5, i0 = (tid & 31) * 4;
        const int nn = n0 + nl;
        const float pv = (nn < NPTS) ? pd[nn] : 0.0f;     // pad n masked at store
        const float lp = __logf(fmaxf(pv, 0.0f) + 1e-5f);
        float s[4], c[4];
#pragma unroll
        for (int j = 0; j < 4; ++j) {
            const float a = exp2f(KREVL2 - (float)(i0 + j) * L2T128) * lp;
            s[j] = __builtin_amdgcn_sinf(a);
            c[j] = __builtin_amdgcn_cosf(a);
        }
        *(float4*)&snq[nl * SNP + i0] = make_float4(s[0], s[1], s[2], s[3]);
        *(float4*)&cnq[nl * SNP + i0] = make_float4(c[0], c[1], c[2], c[3]);
    }
    __syncthreads();

    // ---- build BsP / BsQ, full i in [0,128), one pass ----
    {
        const int bcr = tid >> 2, q = tid & 3;            // c row, 32-i span
        const int bnl = bcr >> 3, bh = bcr & 7;
#pragma unroll
        for (int half = 0; half < 2; ++half) {
            const int ib0 = q * 32 + half * 16;
            unsigned pp[8], qq[8];
#pragma unroll
            for (int g = 0; g < 4; ++g) {
                const int i4 = ib0 + g * 4;
                const float4 s4 = *(const float4*)&snq[bnl * SNP + i4];
                const float4 c4 = *(const float4*)&cnq[bnl * SNP + i4];
                const uint4  w4 = *(const uint4*)&wpk[bh * WPP + i4];
                const float ws0 = blo(w4.x), wc0 = bhi(w4.x);
                const float ws1 = blo(w4.y), wc1 = bhi(w4.y);
                const float ws2 = blo(w4.z), wc2 = bhi(w4.z);
                const float ws3 = blo(w4.w), wc3 = bhi(w4.w);
                const float P0 = ws0*s4.x + wc0*c4.x, Q0 = wc0*s4.x - ws0*c4.x;
                const float P1 = ws1*s4.y + wc1*c4.y, Q1 = wc1*s4.y - ws1*c4.y;
                const float P2 = ws2*s4.z + wc2*c4.z, Q2 = wc2*s4.z - ws2*c4.z;
                const float P3 = ws3*s4.w + wc3*c4.w, Q3 = wc3*s4.w - ws3*c4.w;
                pp[2*g] = pk_bf16(P0, P1);  pp[2*g+1] = pk_bf16(P2, P3);
                qq[2*g] = pk_bf16(Q0, Q1);  qq[2*g+1] = pk_bf16(Q2, Q3);
            }
            *(uint4*)&BsP[bcr * LDK2 + ib0]     = make_uint4(pp[0], pp[1], pp[2], pp[3]);
            *(uint4*)&BsP[bcr * LDK2 + ib0 + 8] = make_uint4(pp[4], pp[5], pp[6], pp[7]);
            *(uint4*)&BsQ[bcr * LDK2 + ib0]     = make_uint4(qq[0], qq[1], qq[2], qq[3]);
            *(uint4*)&BsQ[bcr * LDK2 + ib0 + 8] = make_uint4(qq[4], qq[5], qq[6], qq[7]);
        }
    }
    __syncthreads();

    // ---- MFMA phase: JIT A-frags, 64 MFMAs (2 M-subtiles), no barriers ----
    const int w = tid >> 6, lane = tid & 63, quad = lane >> 4, l16 = lane & 15;
    const float ldr0 = ldm[w * 32 + l16];
    const float ldr1 = ldm[w * 32 + 16 + l16];

    floatx4 acc[2][4];
#pragma unroll
    for (int mi = 0; mi < 2; ++mi)
#pragma unroll
        for (int nf = 0; nf < 4; ++nf) acc[mi][nf] = (floatx4){0.f, 0.f, 0.f, 0.f};

#pragma unroll
    for (int ib = 0; ib < 2; ++ib) {
        frag_u cf[2][2], sf[2][2];                        // [mi][ks]
#pragma unroll
        for (int ks = 0; ks < 2; ++ks) {
            const int kb = ib * 64 + ks * 32 + quad * 8;
            const float4 f0 = *(const float4*)&kfr[kb];
            const float4 f1 = *(const float4*)&kfr[kb + 4];
            const float fr[8] = {f0.x, f0.y, f0.z, f0.w, f1.x, f1.y, f1.z, f1.w};
            float s0[8], c0v[8], s1[8], c1v[8];
#pragma unroll
            for (int j = 0; j < 8; ++j) {
                const float a0 = fr[j] * ldr0;            // revolutions
                const float a1 = fr[j] * ldr1;
                s0[j]  = __builtin_amdgcn_sinf(a0);
                c0v[j] = __builtin_amdgcn_cosf(a0);
                s1[j]  = __builtin_amdgcn_sinf(a1);
                c1v[j] = __builtin_amdgcn_cosf(a1);
            }
#pragma unroll
            for (int r = 0; r < 4; ++r) {
                cf[0][ks].u[r] = pk_bf16(c0v[2*r], c0v[2*r+1]);
                sf[0][ks].u[r] = pk_bf16(s0[2*r],  s0[2*r+1]);
                cf[1][ks].u[r] = pk_bf16(c1v[2*r], c1v[2*r+1]);
                sf[1][ks].u[r] = pk_bf16(s1[2*r],  s1[2*r+1]);
            }
        }
#pragma unroll
        for (int ks = 0; ks < 2; ++ks) {
            const int koff = ib * 64 + ks * 32 + quad * 8;
#pragma unroll
            for (int nf = 0; nf < 4; ++nf) {
                short8 bp = *(const short8*)&BsP[(nf * 16 + l16) * LDK2 + koff];
                acc[0][nf] = __builtin_amdgcn_mfma_f32_16x16x32_bf16(cf[0][ks].s, bp, acc[0][nf], 0, 0, 0);
                acc[1][nf] = __builtin_amdgcn_mfma_f32_16x16x32_bf16(cf[1][ks].s, bp, acc[1][nf], 0, 0, 0);
                short8 bq = *(const short8*)&BsQ[(nf * 16 + l16) * LDK2 + koff];
                acc[0][nf] = __builtin_amdgcn_mfma_f32_16x16x32_bf16(sf[0][ks].s, bq, acc[0][nf], 0, 0, 0);
                acc[1][nf] = __builtin_amdgcn_mfma_f32_16x16x32_bf16(sf[1][ks].s, bq, acc[1][nf], 0, 0, 0);
            }
        }
    }

    // ---- epilogue (verified): C/D col=lane&15, row=quad*4+reg ----
    const float bias = b[lane & 7];
#pragma unroll
    for (int mi = 0; mi < 2; ++mi) {
#pragma unroll
        for (int nf = 0; nf < 4; ++nf) {
            const int c = c0 + nf * 16 + l16;
            if (c < NCOL) {
                const int n = c >> 3, h = c & 7;
                const int hw = m0 + w * 32 + mi * 16 + quad * 4;
                floatx4 v = acc[mi][nf];
                v.x = fmaxf(v.x + bias, 0.0f);
                v.y = fmaxf(v.y + bias, 0.0f);
                v.z = fmaxf(v.z + bias, 0.0f);
                v.w = fmaxf(v.w + bias, 0.0f);
                *(floatx4*)(out + (size_t)h * TOTAL + (size_t)n * HW_SZ + hw) = v;
            }
        }
    }
}

extern "C" void kernel_launch(void* const* d_in, const int* in_sizes, int n_in,
                              void* d_out, int out_size, void* d_ws, size_t ws_size,
                              hipStream_t stream) {
    const float* pd = (const float*)d_in[0];
    const float* dm = (const float*)d_in[1];
    const float* W  = (const float*)d_in[2];
    const float* b  = (const float*)d_in[3];
    float* out = (float*)d_out;

    dre_v16<<<dim3(MT, CT), 256, 0, stream>>>(pd, dm, W, b, out);
}